// Round 1
// 433.079 us; speedup vs baseline: 1.1264x; 1.1264x over previous
//
#include <hip/hip_runtime.h>
#include <hip/hip_bf16.h>

#define N_    32
#define T_    1600
#define C_    1024
#define S_    200
#define L_    401       // 2*S+1
#define LP_   512       // padded
#define BLANK_ 4
#define LN2_  0.69314718055994531f
#define L2E_  1.44269504088896341f
#define DPF   8

#if __has_builtin(__builtin_amdgcn_exp2f)
#define EXP2(x) __builtin_amdgcn_exp2f(x)
#else
#define EXP2(x) exp2f(x)
#endif
#if __has_builtin(__builtin_amdgcn_rcpf)
#define RCP(x) __builtin_amdgcn_rcpf(x)
#else
#define RCP(x) (1.0f / (x))
#endif

// Kernel 1: one wave per (n,t) row. Wave-shuffle softmax, row staged in LDS,
// gather ext-label classes, write LINEAR probabilities P[n][t][l].
// Junk positions (l > 2*tgt_len[n], never read) are zeroed so their alphas
// stay exactly 0 and never pollute the renorm max in k_ctc.
__global__ __launch_bounds__(256)
void k_softmax_gather(const float* __restrict__ logits,
                      const int* __restrict__ targets,
                      const int* __restrict__ tgt_len,
                      float* __restrict__ P) {
  const int row  = blockIdx.x * 4 + (threadIdx.x >> 6);  // n*T_ + t
  const int lane = threadIdx.x & 63;
  const int wv   = threadIdx.x >> 6;
  const int n    = row / T_;
  const float* x = logits + (size_t)row * C_;
  __shared__ float sh[4][C_];

  float4 v[4];
#pragma unroll
  for (int i = 0; i < 4; ++i)
    v[i] = reinterpret_cast<const float4*>(x)[i * 64 + lane];

  float mx = v[0].x;
#pragma unroll
  for (int i = 0; i < 4; ++i)
    mx = fmaxf(mx, fmaxf(fmaxf(v[i].x, v[i].y), fmaxf(v[i].z, v[i].w)));
#pragma unroll
  for (int i = 1; i < 64; i <<= 1) mx = fmaxf(mx, __shfl_xor(mx, i));

  float s = 0.0f;
#pragma unroll
  for (int i = 0; i < 4; ++i) {
    s += EXP2((v[i].x - mx) * L2E_) + EXP2((v[i].y - mx) * L2E_)
       + EXP2((v[i].z - mx) * L2E_) + EXP2((v[i].w - mx) * L2E_);
  }
#pragma unroll
  for (int i = 1; i < 64; i <<= 1) s += __shfl_xor(s, i);
  float rz = RCP(s);

#pragma unroll
  for (int i = 0; i < 4; ++i)
    reinterpret_cast<float4*>(sh[wv])[i * 64 + lane] = v[i];
  __syncthreads();

  const int* tg = targets + n * S_;
  const int lmax = 2 * tgt_len[n];   // live region: l in [0, 2*tl]
  float* out = P + (size_t)row * LP_;
#pragma unroll
  for (int i = 0; i < 8; ++i) {
    int l = lane + i * 64;
    float p = 0.0f;
    if (l <= lmax) {
      int c = (l & 1) ? tg[(l - 1) >> 1] : BLANK_;
      p = EXP2((sh[wv][c] - mx) * L2E_) * rz;
    }
    out[l] = p;
  }
}

// Kernel 2: f64 linear-space CTC forward, ONE wave per sequence (R5 taught:
// per-step cross-wave barriers cost what they save). Lane owns 8 contiguous
// positions. Even positions (blanks) never skip -> add+mul only; only ONE
// cross-lane value per step (alpha[l-1] for j=0), shuffled one step AHEAD so
// bpermute latency hides under the f64 issue stream.
//
// THIS ROUND: the previous build allocated only 64 VGPRs (rocprof
// VGPR_Count=64) -- the 16-float4 DPF prefetch cannot live in that budget, so
// the compiler sank the loads next to their uses and every step paid cache
// latency (SIMD only ~38% busy). Fix: __launch_bounds__(64, 1) lifts the VGPR
// cap to 512 (only 1 wave/CU runs anyway), and the prefetch is restructured
// as an explicit ping-pong double buffer (A0/B0 <-> A1/B1, 16 steps per outer
// iteration, all indices unroll-constant) so the 16 loads of block k+1 are
// issued ~8 steps (~1200 cyc) before first use. Math / renorm cadence /
// epilogue counts are unchanged.
__global__ __launch_bounds__(64, 1)
void k_ctc(const float* __restrict__ P,
           const int* __restrict__ targets,
           const int* __restrict__ in_len,
           const int* __restrict__ tgt_len,
           float* __restrict__ nll_out) {
  const int n = blockIdx.x;
  const int lane = threadIdx.x;
  const int Tn = in_len[n];
  const float* g = P + (size_t)n * T_ * LP_;
  const int* tg = targets + n * S_;

  // skip multipliers for odd positions j=1,3,5,7 -> label index m0+0..3
  const int m0 = lane * 4;
  auto skv = [&](int m) -> double {
    int mi = (m >= 1 && m < S_) ? m : 1;     // clamp: no OOB read
    return (m >= 1 && m < S_ && tg[mi] != tg[mi - 1]) ? 1.0 : 0.0;
  };
  const double sk1 = skv(m0), sk3 = skv(m0 + 1);
  const double sk5 = skv(m0 + 2), sk7 = skv(m0 + 3);

  double a0 = 0.0, a1 = 0.0, a2 = 0.0, a3 = 0.0;
  double a4 = 0.0, a5 = 0.0, a6 = 0.0, a7 = 0.0;
  double up = 0.0;   // alpha(t-1, lane*8 - 1): shuffled during previous step
  if (lane == 0) { a0 = (double)g[0]; a1 = (double)g[1]; }
  int Etot = 0;      // true alpha = a * 2^Etot (wave-uniform)

  const float* gl = g + lane * 8;
  const int src = (lane + 63) & 63;

  auto step = [&](const float4& A, const float4& B) {
    // a7n/a6n first: lane-local only -> shuffle for NEXT step issues early
    double a7n = (a7 + a6 + sk7 * a5) * (double)B.w;
    double a6n = (a6 + a5) * (double)B.z;
    double upn = __shfl(a7n, src);           // consumed next step
    double a5n = (a5 + a4 + sk5 * a3) * (double)B.y;
    double a4n = (a4 + a3) * (double)B.x;
    double a3n = (a3 + a2 + sk3 * a1) * (double)A.w;
    double a2n = (a2 + a1) * (double)A.z;
    double a1n = (a1 + a0 + sk1 * up) * (double)A.y;  // up: already in regs
    double a0n = (a0 + up) * (double)A.x;             // even: no skip ever
    if (lane == 0) upn = 0.0;                // no predecessor (R1 lesson)
    a0 = a0n; a1 = a1n; a2 = a2n; a3 = a3n;
    a4 = a4n; a5 = a5n; a6 = a6n; a7 = a7n;
    up = upn;
  };

  auto renorm = [&]() {
    int h = max(max(max(__double2hiint(a0), __double2hiint(a1)),
                    max(__double2hiint(a2), __double2hiint(a3))),
                max(max(__double2hiint(a4), __double2hiint(a5)),
                    max(__double2hiint(a6), __double2hiint(a7))));
#pragma unroll
    for (int i = 1; i < 64; i <<= 1) h = max(h, __shfl_xor(h, i));
    int R = 1021 - (h >> 20);   // scale wave max into [2^-2, 2^-1)
    a0 = ldexp(a0, R); a1 = ldexp(a1, R); a2 = ldexp(a2, R); a3 = ldexp(a3, R);
    a4 = ldexp(a4, R); a5 = ldexp(a5, R); a6 = ldexp(a6, R); a7 = ldexp(a7, R);
    up = ldexp(up, R);          // pipelined boundary value rides along
    Etot -= R;
  };

  // load rows [tt, tt..] for one step into a float4 pair (clamped: rows up to
  // T_-1 always exist in P; clamped rows are only prefetch garbage, never
  // consumed by an executed step)
  auto ld = [&](int tt, float4& A, float4& B) {
    if (tt > T_ - 1) tt = T_ - 1;
    const float* p = gl + (size_t)tt * LP_;
    A = *reinterpret_cast<const float4*>(p);
    B = *reinterpret_cast<const float4*>(p + 4);
  };

  float4 A0[DPF], B0[DPF], A1[DPF], B1[DPF];
#pragma unroll
  for (int d = 0; d < DPF; ++d) ld(1 + d, A0[d], B0[d]);

  // invariant at each phase top: A0/B0 (resp. A1/B1) hold rows t..t+DPF-1
  int t = 1;
  int rem = Tn - 1;               // total steps to execute (t = 1..Tn-1)
  int blk = 0;
  while (rem >= 2 * DPF) {
    // phase 1: prefetch next block into A1/B1, compute from A0/B0
#pragma unroll
    for (int d = 0; d < DPF; ++d) ld(t + DPF + d, A1[d], B1[d]);
#pragma unroll
    for (int d = 0; d < DPF; ++d) step(A0[d], B0[d]);
    t += DPF;
    if ((++blk & 3) == 0) renorm();   // every 32 steps; max gap 39 < f64 range
    // phase 2: prefetch next block into A0/B0, compute from A1/B1
#pragma unroll
    for (int d = 0; d < DPF; ++d) ld(t + DPF + d, A0[d], B0[d]);
#pragma unroll
    for (int d = 0; d < DPF; ++d) step(A1[d], B1[d]);
    t += DPF;
    if ((++blk & 3) == 0) renorm();
    rem -= 2 * DPF;
  }
  // rem in [0, 2*DPF-1]; A0/B0 hold rows t..t+DPF-1
  if (rem >= DPF) {
#pragma unroll
    for (int d = 0; d < DPF; ++d) ld(t + DPF + d, A1[d], B1[d]);
#pragma unroll
    for (int d = 0; d < DPF; ++d) step(A0[d], B0[d]);
    t += DPF; rem -= DPF;
    if ((++blk & 3) == 0) renorm();
#pragma unroll
    for (int d = 0; d < DPF; ++d) {
      if (d < rem) step(A1[d], B1[d]);
    }
  } else {
#pragma unroll
    for (int d = 0; d < DPF; ++d) {
      if (d < rem) step(A0[d], B0[d]);
    }
  }

  __shared__ double sa[LP_];
  sa[lane * 8 + 0] = a0; sa[lane * 8 + 1] = a1;
  sa[lane * 8 + 2] = a2; sa[lane * 8 + 3] = a3;
  sa[lane * 8 + 4] = a4; sa[lane * 8 + 5] = a5;
  sa[lane * 8 + 6] = a6; sa[lane * 8 + 7] = a7;
  __syncthreads();
  if (lane == 0) {
    int tl = tgt_len[n];
    double v = sa[2 * tl - 1] + sa[2 * tl];
    int ee;
    double m = frexp(v, &ee);
    nll_out[n] = -LN2_ * ((float)(Etot + ee) + log2f((float)m));
  }
}

__global__ void k_final(const float* __restrict__ nll,
                        const int* __restrict__ tgt_len,
                        float* __restrict__ out) {
  int lane = threadIdx.x;
  float v = 0.0f;
  if (lane < N_) v = nll[lane] / (float)tgt_len[lane];
#pragma unroll
  for (int i = 1; i < 64; i <<= 1) v += __shfl_xor(v, i);
  if (lane == 0) out[0] = v * (1.0f / N_);
}

__global__ void k_sentinel(float* out) { out[0] = -12345.0f; }

extern "C" void kernel_launch(void* const* d_in, const int* in_sizes, int n_in,
                              void* d_out, int out_size, void* d_ws, size_t ws_size,
                              hipStream_t stream) {
  const float* logits = (const float*)d_in[0];
  const int* targets  = (const int*)d_in[1];
  const int* in_len   = (const int*)d_in[2];
  const int* tgt_len  = (const int*)d_in[3];
  float* out = (float*)d_out;

  size_t gbytes = (size_t)N_ * T_ * LP_ * sizeof(float);  // ~104.9 MB
  if (ws_size < gbytes + 256) {
    k_sentinel<<<1, 1, 0, stream>>>(out);
    return;
  }
  float* G = (float*)d_ws;
  float* nll = (float*)((char*)d_ws + gbytes);

  k_softmax_gather<<<(N_ * T_) / 4, 256, 0, stream>>>(logits, targets, tgt_len, G);
  k_ctc<<<N_, 64, 0, stream>>>(G, targets, in_len, tgt_len, nll);
  k_final<<<1, 64, 0, stream>>>(nll, tgt_len, out);
}